// Round 2
// baseline (4746.744 us; speedup 1.0000x reference)
//
#include <hip/hip_runtime.h>
#include <stdint.h>
#include <stddef.h>

// ---------------------------------------------------------------------------
// SNN policy forward: persistent grouped-GEMM implementation for MI355X.
// B=2048, F=256 (2F=512), H=1024, O=256, T=64.
// Grid: 256 blocks = 16 groups (batch tiles of 128 rows) x 16 h-slices (64 h).
// Block: 256 threads = 4 waves arranged 2(M) x 2(N); wave tile = 64m x 32h,
// using v_mfma_f32_32x32x16_f16 with A = spikes {0.0,1.0} (exact),
// B = weights split hi/lo f16 (f32 reproduced to ~2^-22 rel).
// ---------------------------------------------------------------------------

typedef _Float16 v8h  __attribute__((ext_vector_type(8)));
typedef float    v16f __attribute__((ext_vector_type(16)));

// workspace layout (bytes)
#define OFF_WSTM  0ull                 // main W tiles  [hb16][c24][p2][64][72] f16 = 7,077,888
#define OFF_WSTO  7077888ull           // w_out tiles   [hb16][cl8][p2][32][72] f16 = 1,179,648
#define OFF_BITS  8262656ull           // u32 ring [64][2048][48] = 25,165,824
#define OFF_P     33428480ull          // f32 [kh2][par2][2048][256] = 8,388,608
#define OFF_CTR   41817088ull          // u32 [16][64] group barrier counters

#define SLOT_U32  (2048*48)

__device__ __forceinline__ float frn_add(float a, float b){ return __fadd_rn(a,b); }
__device__ __forceinline__ float frn_sub(float a, float b){ return __fsub_rn(a,b); }
__device__ __forceinline__ float frn_mul(float a, float b){ return __fmul_rn(a,b); }

// ---------------------------------------------------------------------------
// prep kernel: tile/convert weights to hi/lo f16, zero slot0 + counters
// ---------------------------------------------------------------------------
__global__ void k_prep(const float* __restrict__ w_in, const float* __restrict__ w_rec,
                       const float* __restrict__ w_out, uint8_t* __restrict__ ws)
{
    const long long stride = (long long)gridDim.x * blockDim.x;
    const long long id = (long long)blockIdx.x * blockDim.x + threadIdx.x;

    _Float16* wm = (_Float16*)(ws + OFF_WSTM);
    for (long long i = id; i < 16LL*24*2*64*72; i += stride) {
        int kk = (int)(i % 72); long long t2 = i / 72;
        int hrow = (int)(t2 % 64); t2 /= 64;
        int p = (int)(t2 % 2);  t2 /= 2;
        int c = (int)(t2 % 24); int hb = (int)(t2 / 24);
        _Float16 val = (_Float16)0.0f;
        if (kk < 64) {
            int h = hb*64 + hrow; int k = c*64 + kk;
            float wv = (k < 512) ? w_in[(size_t)h*512 + k] : w_rec[(size_t)h*1024 + (k - 512)];
            _Float16 hi = (_Float16)wv;
            val = p ? (_Float16)(wv - (float)hi) : hi;
        }
        wm[i] = val;
    }

    _Float16* wo = (_Float16*)(ws + OFF_WSTO);
    for (long long i = id; i < 16LL*8*2*32*72; i += stride) {
        int kk = (int)(i % 72); long long t2 = i / 72;
        int orow = (int)(t2 % 32); t2 /= 32;
        int p = (int)(t2 % 2); t2 /= 2;
        int cl = (int)(t2 % 8); int hb = (int)(t2 / 8);
        _Float16 val = (_Float16)0.0f;
        if (kk < 64) {
            int o = (hb & 7)*32 + orow;
            int zk = (hb >> 3)*512 + cl*64 + kk;
            float wv = w_out[(size_t)o*1024 + zk];
            _Float16 hi = (_Float16)wv;
            val = p ? (_Float16)(wv - (float)hi) : hi;
        }
        wo[i] = val;
    }

    uint32_t* bz = (uint32_t*)(ws + OFF_BITS);
    for (long long i = id; i < SLOT_U32; i += stride) bz[i] = 0u;   // slot 0 (xt(0) overwritten, z(-1)=0)
    uint32_t* ctr = (uint32_t*)(ws + OFF_CTR);
    for (long long i = id; i < 16*64; i += stride) ctr[i] = 0u;
}

// ---------------------------------------------------------------------------
// main persistent kernel
// ---------------------------------------------------------------------------
__global__ __launch_bounds__(256, 1)
void k_snn(const float* __restrict__ x, uint8_t* __restrict__ ws,
           float* __restrict__ outm, const int* __restrict__ seqp)
{
    extern __shared__ uint8_t smem[];
    // smem layout: [0, 36864)  : B stage, 2 slots x [p2][64][72] f16
    //              [36864, ..) : bits LDS [128][49] u32 (25088B); aliased by P-tile [128][33] f32

    const int tid  = threadIdx.x;
    const int lane = tid & 63;
    const int wv4  = tid >> 6;        // wave id 0..3
    const int mi   = wv4 >> 1;        // M half
    const int nj   = wv4 & 1;         // N half
    const int q    = lane >> 5;       // k-octet half
    const int ln   = lane & 31;

    const int b  = blockIdx.x;
    const int bb = b >> 4;                                 // group / batch tile
    const int hb = ((b & 7) << 1) | ((b >> 3) & 1);        // h-slice, XCD-local pairs
    const int rowBase = bb * 128;
    const int kh = hb >> 3;           // out-GEMM k half
    const int c0 = 8 + kh * 8;        // first out-duty chunk

    int T = *seqp; if (T > 64) T = 64; if (T < 1) T = 1;

    const int oo = (hb << 4) + (tid & 15);
    const int r8 = (tid >> 4) << 3;

    float io8[8], vo8[8], mx8[8];
#pragma unroll
    for (int i = 0; i < 8; ++i) { io8[i] = 0.f; vo8[i] = 0.f; mx8[i] = 0.f; }

    v16f zv;
#pragma unroll
    for (int k = 0; k < 16; ++k) zv[k] = 0.f;
    v16f vS[2], iS[2];
    vS[0] = zv; vS[1] = zv; iS[0] = zv; iS[1] = zv;

    // encoder state (threads 0..127 own one row x 32 features)
    float ve[32], cc[32];
    if (tid < 128) {
        const float* xr = x + (size_t)(rowBase + tid) * 256;
        const int f0 = (hb & 7) * 32;
        const float sgn = (hb < 8) ? 50.0f : -50.0f;
#pragma unroll
        for (int f = 0; f < 32; ++f) {
            float cv = frn_mul(sgn, xr[f0 + f]);
            cc[f] = fmaxf(cv, 0.0f);
            ve[f] = 0.0f;
        }
    }

    uint32_t* const bitsRing = (uint32_t*)(ws + OFF_BITS);
    uint32_t* const bitsL = (uint32_t*)(smem + 36864);
    uint32_t* const ctr = (uint32_t*)(ws + OFF_CTR) + bb * 64;
    const uint4* const wstg = (const uint4*)(ws + OFF_WSTM) + (size_t)(hb * 24) * 1152;
    uint4* const Bs = (uint4*)smem;

    auto enc_step = [&](int dstSlot) {
        if (tid < 128) {
            uint32_t wd = 0;
#pragma unroll
            for (int f = 0; f < 32; ++f) {
                float vv = ve[f];
                vv = frn_add(vv, frn_mul(0.1f, frn_add(frn_sub(0.0f, vv), cc[f])));
                bool zz = frn_sub(vv, 1.0f) > 0.0f;
                ve[f] = zz ? 0.0f : vv;
                wd |= zz ? (1u << f) : 0u;
            }
            bitsRing[(size_t)dstSlot * SLOT_U32 + (size_t)(rowBase + tid) * 48 + hb] = wd;
        }
    };

    auto gbar = [&](int phase) {
        __syncthreads();
        if (tid == 0) {
            __hip_atomic_fetch_add(ctr, 1u, __ATOMIC_RELEASE, __HIP_MEMORY_SCOPE_AGENT);
            const uint32_t tgt = 16u * (uint32_t)(phase + 1);
            while (__hip_atomic_load(ctr, __ATOMIC_RELAXED, __HIP_MEMORY_SCOPE_AGENT) < tgt)
                __builtin_amdgcn_s_sleep(1);
            asm volatile("" ::: "memory");
        }
        __syncthreads();
    };

    enc_step(0);   // xt(0) -> slot 0

    for (int t = 0; ; ++t) {
        gbar(t);

        // ---- readout owner phase: io(t-2), vo(t-1), running max ----
        if (t >= 2) {
            const uint32_t* Pg = (const uint32_t*)(ws + OFF_P);
#pragma unroll
            for (int i = 0; i < 8; ++i) {
                size_t base = ((size_t)(t & 1) * 2048 + (size_t)(rowBase + r8 + i)) * 256 + oo;
                uint32_t ra_ = __hip_atomic_load(Pg + base, __ATOMIC_RELAXED, __HIP_MEMORY_SCOPE_AGENT);
                uint32_t rb_ = __hip_atomic_load(Pg + 2ull*2048*256 + base, __ATOMIC_RELAXED, __HIP_MEMORY_SCOPE_AGENT);
                float Pa = __uint_as_float(ra_);
                float Pb = __uint_as_float(rb_);
                float iod = frn_sub(io8[i], frn_mul(0.2f, io8[i]));
                io8[i] = frn_add(iod, frn_add(Pa, Pb));
            }
        }
        if (t >= 1) {
#pragma unroll
            for (int i = 0; i < 8; ++i) {
                vo8[i] = frn_add(vo8[i], frn_mul(0.1f, frn_sub(io8[i], vo8[i])));
                mx8[i] = fmaxf(mx8[i], vo8[i]);
            }
        }
        if (t == T) break;

        // ---- load this iter's spike bits (slot t) into LDS [128][49] ----
        {
            const uint4* src = (const uint4*)(bitsRing + (size_t)t * SLOT_U32 + (size_t)rowBase * 48);
#pragma unroll
            for (int i2 = 0; i2 < 6; ++i2) {
                int idx = tid + i2 * 256;          // 0..1535 uint4
                uint4 d = src[idx];
                int r = idx / 12, wq = idx % 12;
                uint32_t* dst = bitsL + r * 49 + wq * 4;
                dst[0] = d.x; dst[1] = d.y; dst[2] = d.z; dst[3] = d.w;
            }
        }

        // ---- stage chunk 0 ----
        uint4 pf[5];
        const int npf = (tid < 128) ? 5 : 4;
        {
            const uint4* g = wstg;
#pragma unroll
            for (int k2 = 0; k2 < 5; ++k2) if (k2 < npf) pf[k2] = g[tid + k2 * 256];
            __syncthreads();   // bits LDS visible
#pragma unroll
            for (int k2 = 0; k2 < 5; ++k2) if (k2 < npf) Bs[tid + k2 * 256] = pf[k2];
            __syncthreads();
        }

        v16f acc[2], oacc[2];
        acc[0] = zv; acc[1] = zv; oacc[0] = zv; oacc[1] = zv;
        const bool dout = (t >= 1);

        for (int c = 0; c < 24; ++c) {
            if (c < 23) {
                const uint4* g = wstg + (size_t)(c + 1) * 1152;
#pragma unroll
                for (int k2 = 0; k2 < 5; ++k2) if (k2 < npf) pf[k2] = g[tid + k2 * 256];
            }
            const bool odut = dout && (c >= c0) && (c < c0 + 8) && ((((c - c0) >> 2) & 1) == nj);
            uint4 wof[8];
            if (odut) {
                int cl = c - c0;
                const uint8_t* wob = ws + OFF_WSTO + (size_t)((hb * 8 + cl) * 2) * 32 * 72 * 2;
#pragma unroll
                for (int kc = 0; kc < 4; ++kc)
#pragma unroll
                    for (int p = 0; p < 2; ++p)
                        wof[kc * 2 + p] = *(const uint4*)(wob + ((size_t)(p * 32 + ln) * 72 + kc * 16 + q * 8) * 2);
            }

            const _Float16* Bt = (const _Float16*)(smem + (c & 1) * 18432);
            uint32_t wb[2];
#pragma unroll
            for (int kc = 0; kc < 4; ++kc) {
                if ((kc & 1) == 0) {
#pragma unroll
                    for (int Mt = 0; Mt < 2; ++Mt)
                        wb[Mt] = bitsL[(mi * 64 + Mt * 32 + ln) * 49 + (c * 2 + (kc >> 1))];
                }
                v8h A[2];
#pragma unroll
                for (int Mt = 0; Mt < 2; ++Mt) {
                    const uint32_t wv2 = wb[Mt];
                    const int sh = ((kc & 1) << 4) + (q << 3);
                    union { uint32_t u[4]; v8h h; } ua;
#pragma unroll
                    for (int j2 = 0; j2 < 4; ++j2) {
                        uint32_t pr = (wv2 >> (sh + 2 * j2)) & 3u;
                        // exact {0,1} spikes: bit0 -> low f16, bit1 -> high f16
                        uint32_t lo_ = (pr & 1u) ? 0x00003C00u : 0u;
                        uint32_t hi_ = (pr & 2u) ? 0x3C000000u : 0u;
                        ua.u[j2] = lo_ | hi_;
                    }
                    A[Mt] = ua.h;
                }
                const _Float16* brow = Bt + (size_t)(nj * 32 + ln) * 72 + kc * 16 + q * 8;
                v8h Bh = *(const v8h*)brow;
                v8h Bl = *(const v8h*)(brow + 64 * 72);
#pragma unroll
                for (int Mt = 0; Mt < 2; ++Mt) {
                    acc[Mt] = __builtin_amdgcn_mfma_f32_32x32x16_f16(A[Mt], Bh, acc[Mt], 0, 0, 0);
                    acc[Mt] = __builtin_amdgcn_mfma_f32_32x32x16_f16(A[Mt], Bl, acc[Mt], 0, 0, 0);
                }
                if (odut) {
                    union { uint4 u; v8h h; } bo0, bo1;
                    bo0.u = wof[kc * 2 + 0]; bo1.u = wof[kc * 2 + 1];
#pragma unroll
                    for (int Mt = 0; Mt < 2; ++Mt) {
                        oacc[Mt] = __builtin_amdgcn_mfma_f32_32x32x16_f16(A[Mt], bo0.h, oacc[Mt], 0, 0, 0);
                        oacc[Mt] = __builtin_amdgcn_mfma_f32_32x32x16_f16(A[Mt], bo1.h, oacc[Mt], 0, 0, 0);
                    }
                }
            }
            if (c < 23) {
                uint4* dst = Bs + ((c + 1) & 1) * 1152;
#pragma unroll
                for (int k2 = 0; k2 < 5; ++k2) if (k2 < npf) dst[tid + k2 * 256] = pf[k2];
            }
            __syncthreads();
        }

        // ---- hidden state update + spike bit pack ----
        uint32_t zw[2];
#pragma unroll
        for (int Mt = 0; Mt < 2; ++Mt) {
            uint32_t zzw = 0;
#pragma unroll
            for (int r = 0; r < 16; ++r) {
                float iold = iS[Mt][r];
                float vd = frn_add(vS[Mt][r], frn_mul(0.1f, frn_add(frn_sub(0.0f, vS[Mt][r]), iold)));
                bool z = frn_sub(vd, 1.0f) > 0.0f;
                vS[Mt][r] = z ? 0.0f : vd;
                float idc = frn_sub(iold, frn_mul(0.2f, iold));
                iS[Mt][r] = frn_add(idc, acc[Mt][r]);
                unsigned long long bal = __ballot(z);
                int ra = (r & 3) + ((r >> 2) << 3);
                if (lane == ra)     zzw = (uint32_t)bal;
                if (lane == ra + 4) zzw = (uint32_t)(bal >> 32);
            }
            zw[Mt] = zzw;
        }
        if (t < T - 1) {
            if (lane < 32) {
                uint32_t* bg = bitsRing + (size_t)(t + 1) * SLOT_U32;
#pragma unroll
                for (int Mt = 0; Mt < 2; ++Mt)
                    bg[(size_t)(rowBase + mi * 64 + Mt * 32 + lane) * 48 + 16 + hb * 2 + nj] = zw[Mt];
            }
            enc_step(t + 1);
        }

        // ---- combine readout partials in LDS (aliases bits region), write P(t-1) ----
        if (t >= 1) {
            __syncthreads();
            float* Pt = (float*)(smem + 36864);
            if (nj == 0) {
#pragma unroll
                for (int Mt = 0; Mt < 2; ++Mt)
#pragma unroll
                    for (int r = 0; r < 16; ++r) {
                        int rl = mi * 64 + Mt * 32 + (r & 3) + ((r >> 2) << 3) + (q << 2);
                        Pt[rl * 33 + ln] = oacc[Mt][r];
                    }
            }
            __syncthreads();
            if (nj == 1) {
#pragma unroll
                for (int Mt = 0; Mt < 2; ++Mt)
#pragma unroll
                    for (int r = 0; r < 16; ++r) {
                        int rl = mi * 64 + Mt * 32 + (r & 3) + ((r >> 2) << 3) + (q << 2);
                        Pt[rl * 33 + ln] = frn_add(Pt[rl * 33 + ln], oacc[Mt][r]);
                    }
            }
            __syncthreads();
            float* Pg = (float*)(ws + OFF_P) + ((size_t)(kh * 2 + ((t + 1) & 1)) * 2048 + rowBase) * 256;
#pragma unroll
            for (int i2 = 0; i2 < 16; ++i2) {
                int idx = tid + i2 * 256;      // 0..4095
                int rl = idx >> 5, cl2 = idx & 31;
                Pg[(size_t)rl * 256 + (hb & 7) * 32 + cl2] = Pt[rl * 33 + cl2];
            }
        }
    }

    // ---- write per-row max voltages ----
#pragma unroll
    for (int i = 0; i < 8; ++i)
        outm[(size_t)(rowBase + r8 + i) * 256 + oo] = mx8[i];
}

// ---------------------------------------------------------------------------
// softmax over O=256, in-place on d_out
// ---------------------------------------------------------------------------
__global__ void k_sm(float* __restrict__ o)
{
    const int lane = threadIdx.x & 63;
    const int wv4 = threadIdx.x >> 6;
    const int row = blockIdx.x * 8 + wv4 * 2 + (lane >> 5);
    const int ln = lane & 31;
    float* pr = o + (size_t)row * 256;
    float v[8];
#pragma unroll
    for (int i = 0; i < 8; ++i) v[i] = pr[ln + i * 32];
    float m = v[0];
#pragma unroll
    for (int i = 1; i < 8; ++i) m = fmaxf(m, v[i]);
#pragma unroll
    for (int off = 16; off; off >>= 1) m = fmaxf(m, __shfl_xor(m, off, 32));
    float s = 0.f;
#pragma unroll
    for (int i = 0; i < 8; ++i) { v[i] = expf(v[i] - m); s += v[i]; }
#pragma unroll
    for (int off = 16; off; off >>= 1) s += __shfl_xor(s, off, 32);
#pragma unroll
    for (int i = 0; i < 8; ++i) pr[ln + i * 32] = v[i] / s;
}

// ---------------------------------------------------------------------------
extern "C" void kernel_launch(void* const* d_in, const int* in_sizes, int n_in,
                              void* d_out, int out_size, void* d_ws, size_t ws_size,
                              hipStream_t stream)
{
    const float* x     = (const float*)d_in[0];
    const float* w_in  = (const float*)d_in[1];
    const float* w_rec = (const float*)d_in[2];
    const float* w_out = (const float*)d_in[3];
    const int*   seq   = (const int*)d_in[4];
    uint8_t* ws = (uint8_t*)d_ws;
    float* out = (float*)d_out;

    k_prep<<<1024, 256, 0, stream>>>(w_in, w_rec, w_out, ws);

    // 61952 B dynamic LDS — MUST stay under the 64 KiB per-workgroup dispatch
    // limit (requesting more silently rejects the launch -> uniform softmax).
    k_snn<<<256, 256, 61952, stream>>>(x, ws, out, seq);
    k_sm<<<256, 256, 0, stream>>>(out);
}